// Round 11
// baseline (385.815 us; speedup 1.0000x reference)
//
#include <hip/hip_runtime.h>
#include <stdint.h>

// Spiking ConvColumn: temporal PWL-response conv + winner-takes-all.
//   input_spikes [16, 2, 64, 64, 100] fp32 (binary)
//   weight       [32, 2, 3, 3]        fp32 in [0,1]
//   output       [16, 32, 31, 31, 149] fp32 (one-hot spikes)
#define NXS 31
#define NYS 31
#define TP 149
#define TT 100
#define RSTRIDE 104         // u32/row: 101 entries + 3 spare; %4==0 keeps b128
                            // alignment; LDS = 54*104*4 = 22.5 KB -> 7 blk/CU
#define NROWS 54            // 2 ci * 3 ky * 9 cols (4 sites share 9 cols)
#define CSTRIDE 143189u     // 961*149, channel stride in d_out (odd: %4==1)

// Block = 4 waves = sites x0..x0+3 sharing one table set (9 columns).
// Wave lanes: 0-31 = 32 ch x trains 0-8 (ci=0); 32-63 = same ch x 9-17 (ci=1).
// Table entry k = (C[k]<<16)|M[k]: C = #spikes before time k, M = sum times.
//
// Pipeline: build -> barrier -> ISSUE zero-fill stores -> scan (LDS-only,
// stores drain underneath) -> barrier (vmcnt drain) -> scatter 1.0s.
__global__ __launch_bounds__(256) void snn_wta(
    const float* __restrict__ in,
    const float* __restrict__ weight,
    float* __restrict__ out)
{
    __shared__ uint32_t tbl[NROWS * RSTRIDE];

    const int tid  = threadIdx.x;
    const int wave = tid >> 6;
    const int lane = tid & 63;
    const int half = lane >> 5;
    const int ch   = lane & 31;

    const int bi = blockIdx.x;
    const int xg = bi & 7;                // 8 x-groups of 4 (last has 3)
    const int y  = (bi >> 3) % NYS;
    const int b  = bi / (8 * NYS);
    const int x0 = xg * 4;
    const int x  = x0 + wave;             // this wave's site (x>=31 inactive)

    // per-lane response params: r(tau)=tau/16 for tau<=m=floor(16w);
    // (48w-tau)/32 for m<tau<=n=ceil(48w)-1.
    float wA[9]; int mA[9], nA[9];
    {
        const float* wrow = weight + ch * 18 + half * 9;
#pragma unroll
        for (int j = 0; j < 9; ++j) {
            float w = wrow[j];
            float a48 = 48.0f * w;
            int m = (int)floorf(16.0f * w);
            int n = (int)ceilf(a48) - 1;
            if (n < m) n = m;
            wA[j] = a48; mA[j] = m; nA[j] = n;
        }
    }

    // ---- build 54 rows; row r owned by one lane (waves split the rows).
    // Tree-form prefix: 25-step carry chain, b128 entry stores.
    {
        const int r = lane + 14 * wave;    // lanes 0..13 of each wave
        if (lane < 14 && r < NROWS) {
            const int ci = r / 27, rem = r % 27;
            const int ky = rem / 9, col = rem % 9;
            const int h = 2 * y + ky, wc = 2 * x0 + col;
            if (wc < 64) {                 // xg=7,col=8 is OOB and unused
                const float4* rowp = (const float4*)(in +
                    (size_t)(((b * 2 + ci) * 64 + h) * 64 + wc) * TT);
                uint32_t* t = tbl + r * RSTRIDE;      // entry-0, 16B aligned
                uint32_t run = 0;
#pragma unroll 5
                for (int chunk = 0; chunk < 25; ++chunk) {
                    float4 v = rowp[chunk];
                    const uint32_t u = chunk * 4;
                    uint32_t i0 = (v.x > 0.5f) ? ((1u << 16) | u)       : 0u;
                    uint32_t i1 = (v.y > 0.5f) ? ((1u << 16) | (u + 1)) : 0u;
                    uint32_t i2 = (v.z > 0.5f) ? ((1u << 16) | (u + 2)) : 0u;
                    uint32_t i3 = (v.w > 0.5f) ? ((1u << 16) | (u + 3)) : 0u;
                    uint32_t s01 = i0 + i1;
                    uint32_t e1 = run + i0;
                    uint32_t e2 = run + s01;
                    uint32_t e3 = e2 + i2;
                    *((uint4*)(t + u)) = make_uint4(run, e1, e2, e3);
                    run = e3 + i3;         // single dependent add per chunk
                }
                t[100] = run;              // total = entry 100
            }
        }
    }
    __syncthreads();

    // ---- issue the zero-fill NOW: stores drain while the scan computes ----
    const int nsite = (NXS - x0) < 4 ? (NXS - x0) : 4;
    const int span = nsite * TP;           // 447 or 596 contiguous dwords
    const uint32_t base0 =
        ((uint32_t)(b * 32) * 961u + (uint32_t)(y * NYS + x0)) * (uint32_t)TP;
    const float4 z4 = make_float4(0.f, 0.f, 0.f, 0.f);

    // head + tail dwords (alignment rotates per channel: CSTRIDE % 4 == 1).
    {
        const int c = tid >> 3, slot = tid & 7;      // 32 ch x 8 slots
        const uint32_t st = base0 + (uint32_t)c * CSTRIDE;
        const int a = (int)((0u - st) & 3u);
        const int nb = (span - a) >> 2;
        const int tail = span - a - 4 * nb;          // 0..3
        if (slot < a)                out[(size_t)st + slot] = 0.0f;
        else if (slot >= 3 && slot - 3 < tail)
            out[(size_t)st + a + 4 * nb + (slot - 3)] = 0.0f;
    }
    // aligned float4 body: flattened over (channel, chunk), 19 iters/thread
    for (int i = tid; i < 32 * 152; i += 256) {
        const int c = i / 152, k = i - c * 152;
        const uint32_t st = base0 + (uint32_t)c * CSTRIDE;
        const int a = (int)((0u - st) & 3u);
        const int nb = (span - a) >> 2;
        if (k < nb)
            *((float4*)(out + (size_t)st + a) + k) = z4;
    }

    // ---- scalar jump-scan WTA (LDS + VALU only: lgkmcnt, not vmcnt,
    // so the zero-fill stores above stay in flight underneath) ----
    uint32_t m0 = 0, m1 = 0, m2 = 0, m3 = 0, m4 = 0;   // 149-bit spike mask
    if (x < NXS) {
        const uint32_t* Tq = tbl + (half * 27 + 2 * wave) * RSTRIDE;
        int tp = 1;                        // tp=0: empty window, no spike
        while (tp < TP) {
            const int t1 = tp - 1;
            const float ft1 = (float)t1;
            const int b0 = (tp < TT) ? tp : TT;          // uniform per half
            uint32_t P0 = 0, P1 = 0, P2 = 0;
            float F = 0.0f;                // sum_j 48w_j * dc2_j
#pragma unroll
            for (int j = 0; j < 9; ++j) {
                const int roff = ((j / 3) * 9 + (j % 3)) * RSTRIDE; // const
                int i1 = t1 - mA[j]; i1 = i1 < 0 ? 0 : (i1 > TT ? TT : i1);
                int i2 = t1 - nA[j]; i2 = i2 < 0 ? 0 : (i2 > TT ? TT : i2);
                uint32_t p0 = Tq[roff + b0];
                uint32_t p1 = Tq[roff + i1];
                uint32_t p2 = Tq[roff + i2];
                P0 += p0; P1 += p1; P2 += p2;
                F += wA[j] * (float)(int)((p1 - p2) >> 16);
            }
            // packed sums/differences carry-free: sum C<=900, sum M<=44550.
            const uint32_t D1 = P0 - P1;   // rising window totals
            const uint32_t D2 = P1 - P2;   // falling window totals
            float pot = (ft1 * (float)(D1 >> 16) - (float)(D1 & 0xffffu)) * 0.0625f
                      + (F - ft1 * (float)(D2 >> 16) + (float)(D2 & 0xffffu)) * 0.03125f;
            pot += __shfl_xor(pot, 32);    // combine the two train halves

            if (__ballot(pot > 5.4f)) {    // any channel spikes this step?
                // argmax over 32 channels; ties -> lowest ch (jnp.argmax)
                float v = pot; int c = ch;
#pragma unroll
                for (int mk = 16; mk >= 1; mk >>= 1) {
                    float vo = __shfl_xor(v, mk);
                    int co   = __shfl_xor(c, mk);
                    if (vo > v || (vo == v && co < c)) { v = vo; c = co; }
                }
                if (c == ch) {
                    const uint32_t bit = 1u << (tp & 31);
                    switch (tp >> 5) {     // wave-uniform branch
                        case 0: m0 |= bit; break;
                        case 1: m1 |= bit; break;
                        case 2: m2 |= bit; break;
                        case 3: m3 |= bit; break;
                        default: m4 |= bit; break;
                    }
                }
                tp += 48;                  // dep=47 refractory skip
            } else {
                tp += 1;
            }
        }
    }

    __syncthreads();   // drains vmcnt: all zeros landed before the ones below

    // ---- scatter the 1.0s straight from mask registers ----
    if (x < NXS && lane < 32) {
        const size_t rb = (size_t)(((b * 32 + ch) * 961) + y * NYS + x) * TP;
        uint32_t mw[5] = { m0, m1, m2, m3, m4 };
#pragma unroll
        for (int w = 0; w < 5; ++w) {
            uint32_t mm = mw[w];
            while (mm) {                   // <=4 spikes total per (site,ch)
                const int t = __builtin_ctz(mm);
                mm &= mm - 1;
                out[rb + 32 * w + t] = 1.0f;
            }
        }
    }
}

extern "C" void kernel_launch(void* const* d_in, const int* in_sizes, int n_in,
                              void* d_out, int out_size, void* d_ws, size_t ws_size,
                              hipStream_t stream) {
    const float* in = (const float*)d_in[0];   // input_spikes
    const float* wt = (const float*)d_in[1];   // weight
    float* out = (float*)d_out;

    // grid: 16 b x 31 y x 8 x-groups (last group covers 3 sites)
    hipLaunchKernelGGL(snn_wta, dim3(16 * NYS * 8), dim3(256), 0, stream,
                       in, wt, out);
}

// Round 12
// 383.527 us; speedup vs baseline: 1.0060x; 1.0060x over previous
//
#include <hip/hip_runtime.h>
#include <stdint.h>

// Spiking ConvColumn: temporal PWL-response conv + winner-takes-all.
//   input_spikes [16, 2, 64, 64, 100] fp32 (binary)
//   weight       [32, 2, 3, 3]        fp32 in [0,1]
//   output       [16, 32, 31, 31, 149] fp32 (one-hot spikes)
#define NXS 31
#define NYS 31
#define TP 149
#define TT 100
#define GUARD 48            // zero guard below entry 0: i = t1-n >= -47
#define RSTRIDE 152         // u32/row: 48 guard + 101 entries + pads; %4==0
                            // keeps b128 alignment. LDS 54*152*4 = 32.8 KB.
#define NROWS 54            // 2 ci * 3 ky * 9 cols (4 sites share 9 cols)
#define CSTRIDE 143189u     // 961*149, channel stride in d_out (odd: %4==1)

// Block = 4 waves = sites x0..x0+3 sharing one table set (9 columns).
// Wave lanes: 0-31 = 32 ch x trains 0-8 (ci=0); 32-63 = same ch x 9-17 (ci=1).
// Table entry k = (C[k]<<16)|M[k]: C = #spikes before time k, M = sum times.
// Row layout [48 zeros | entries 0..100 | pad 101=total]: pair reads (i,i+1)
// via ds_read2_b32 give exact clamp semantics for steps tp and tp+1.
__global__ __launch_bounds__(256) void snn_wta(
    const float* __restrict__ in,
    const float* __restrict__ weight,
    float* __restrict__ out)
{
    __shared__ uint32_t tbl[NROWS * RSTRIDE];

    const int tid  = threadIdx.x;
    const int wave = tid >> 6;
    const int lane = tid & 63;
    const int half = lane >> 5;
    const int ch   = lane & 31;

    const int bi = blockIdx.x;
    const int xg = bi & 7;                // 8 x-groups of 4 (last has 3)
    const int y  = (bi >> 3) % NYS;
    const int b  = bi / (8 * NYS);
    const int x0 = xg * 4;
    const int x  = x0 + wave;             // this wave's site (x>=31 inactive)

    // per-lane response params: r(tau)=tau/16 for tau<=m=floor(16w);
    // (48w-tau)/32 for m<tau<=n=ceil(48w)-1.
    float wA[9]; int mA[9], nA[9];
    {
        const float* wrow = weight + ch * 18 + half * 9;
#pragma unroll
        for (int j = 0; j < 9; ++j) {
            float w = wrow[j];
            float a48 = 48.0f * w;
            int m = (int)floorf(16.0f * w);
            int n = (int)ceilf(a48) - 1;
            if (n < m) n = m;
            wA[j] = a48; mA[j] = m; nA[j] = n;
        }
    }

    // ---- build 54 rows; row r owned by one lane (waves split the rows).
    // Tree-form prefix: 25-step carry chain, b128 entry stores.
    {
        const int r = lane + 14 * wave;    // lanes 0..13 of each wave
        if (lane < 14 && r < NROWS) {
            const int ci = r / 27, rem = r % 27;
            const int ky = rem / 9, col = rem % 9;
            const int h = 2 * y + ky, wc = 2 * x0 + col;
            uint32_t* rb = tbl + r * RSTRIDE;         // 16-B aligned
            // zero the 48-dword guard (12 x b128)
#pragma unroll
            for (int q = 0; q < 12; ++q)
                ((uint4*)rb)[q] = make_uint4(0u, 0u, 0u, 0u);
            if (wc < 64) {                 // xg=7,col=8 is OOB and unused
                const float4* rowp = (const float4*)(in +
                    (size_t)(((b * 2 + ci) * 64 + h) * 64 + wc) * TT);
                uint32_t* t = rb + GUARD;  // entry-0 pointer, 16-B aligned
                uint32_t run = 0;
#pragma unroll 5
                for (int chunk = 0; chunk < 25; ++chunk) {
                    float4 v = rowp[chunk];
                    const uint32_t u = chunk * 4;
                    uint32_t i0 = (v.x > 0.5f) ? ((1u << 16) | u)       : 0u;
                    uint32_t i1 = (v.y > 0.5f) ? ((1u << 16) | (u + 1)) : 0u;
                    uint32_t i2 = (v.z > 0.5f) ? ((1u << 16) | (u + 2)) : 0u;
                    uint32_t i3 = (v.w > 0.5f) ? ((1u << 16) | (u + 3)) : 0u;
                    uint32_t s01 = i0 + i1;
                    uint32_t e1 = run + i0;
                    uint32_t e2 = run + s01;
                    uint32_t e3 = e2 + i2;
                    *((uint4*)(t + u)) = make_uint4(run, e1, e2, e3);
                    run = e3 + i3;         // single dependent add per chunk
                }
                t[100] = run;              // total = entry 100
                t[101] = run;              // pad: pair read at 100 -> (tot,tot)
            } else {
                uint32_t* t = rb + GUARD;
#pragma unroll
                for (int q = 0; q < 26; ++q)
                    ((uint4*)t)[q] = make_uint4(0u, 0u, 0u, 0u);
            }
        }
    }
    __syncthreads();

    // ---- pair-step jump-scan WTA: evaluate tp and tp+1 with the SAME LDS
    // instruction count (ds_read2_b32 returns adjacent entries). Step tp+1
    // is used only if tp does not fire -> exact sequential semantics.
    uint32_t m0 = 0, m1 = 0, m2 = 0, m3 = 0, m4 = 0;   // 149-bit spike mask
    if (x < NXS) {
        const uint32_t* Tq = tbl + (half * 27 + 2 * wave) * RSTRIDE + GUARD;
        int tp = 1;                        // tp=0: empty window, no spike
        while (tp < TP) {
            const int t1 = tp - 1;
            const int b0 = (tp < TT) ? tp : TT;          // uniform per half
            uint32_t P0a = 0, P1a = 0, P2a = 0;
            uint32_t P0b = 0, P1b = 0, P2b = 0;
            float Fa = 0.0f, Fb = 0.0f;    // sum_j 48w_j * dc2_j
#pragma unroll
            for (int j = 0; j < 9; ++j) {
                const int roff = ((j / 3) * 9 + (j % 3)) * RSTRIDE; // const
                const uint32_t* tj = Tq + roff;
                int i1 = t1 - mA[j]; i1 = i1 > TT ? TT : i1;  // >= -47: guard
                int i2 = t1 - nA[j]; i2 = i2 > TT ? TT : i2;
                uint32_t p0a = tj[b0], p0b = tj[b0 + 1];      // ds_read2
                uint32_t p1a = tj[i1], p1b = tj[i1 + 1];
                uint32_t p2a = tj[i2], p2b = tj[i2 + 1];
                P0a += p0a; P1a += p1a; P2a += p2a;
                P0b += p0b; P1b += p1b; P2b += p2b;
                Fa += wA[j] * (float)(int)((p1a - p2a) >> 16);
                Fb += wA[j] * (float)(int)((p1b - p2b) >> 16);
            }
            // packed sums/differences carry-free: sum C<=900, sum M<=44550.
            float pota, potb;
            {
                const float ft1 = (float)t1;
                const uint32_t D1 = P0a - P1a, D2 = P1a - P2a;
                pota = (ft1 * (float)(D1 >> 16) - (float)(D1 & 0xffffu)) * 0.0625f
                     + (Fa - ft1 * (float)(D2 >> 16) + (float)(D2 & 0xffffu)) * 0.03125f;
                pota += __shfl_xor(pota, 32);
            }
            {
                const float ft2 = (float)(t1 + 1);
                const uint32_t D1 = P0b - P1b, D2 = P1b - P2b;
                potb = (ft2 * (float)(D1 >> 16) - (float)(D1 & 0xffffu)) * 0.0625f
                     + (Fb - ft2 * (float)(D2 >> 16) + (float)(D2 & 0xffffu)) * 0.03125f;
                potb += __shfl_xor(potb, 32);
            }

            int ts;                        // firing step, or -1
            float v;
            if (__ballot(pota > 5.4f)) { ts = tp; v = pota; }
            else if (tp + 1 < TP && __ballot(potb > 5.4f)) { ts = tp + 1; v = potb; }
            else { tp += 2; continue; }

            // argmax over 32 channels; ties -> lowest ch (jnp.argmax)
            int c = ch;
#pragma unroll
            for (int mk = 16; mk >= 1; mk >>= 1) {
                float vo = __shfl_xor(v, mk);
                int co   = __shfl_xor(c, mk);
                if (vo > v || (vo == v && co < c)) { v = vo; c = co; }
            }
            if (c == ch) {
                const uint32_t bit = 1u << (ts & 31);
                switch (ts >> 5) {         // wave-uniform branch
                    case 0: m0 |= bit; break;
                    case 1: m1 |= bit; break;
                    case 2: m2 |= bit; break;
                    case 3: m3 |= bit; break;
                    default: m4 |= bit; break;
                }
            }
            tp = ts + 48;                  // dep=47 refractory skip
        }
    }

    // ---- epilogue part 1: block-wide float4 ZERO-fill of the 4-site span ----
    const int nsite = (NXS - x0) < 4 ? (NXS - x0) : 4;
    const int span = nsite * TP;           // 447 or 596 contiguous dwords
    const uint32_t base0 =
        ((uint32_t)(b * 32) * 961u + (uint32_t)(y * NYS + x0)) * (uint32_t)TP;
    const float4 z4 = make_float4(0.f, 0.f, 0.f, 0.f);

    // head + tail dwords (alignment rotates per channel: CSTRIDE % 4 == 1).
    {
        const int c = tid >> 3, slot = tid & 7;      // 32 ch x 8 slots
        const uint32_t st = base0 + (uint32_t)c * CSTRIDE;
        const int a = (int)((0u - st) & 3u);
        const int nb = (span - a) >> 2;
        const int tail = span - a - 4 * nb;          // 0..3
        if (slot < a)                out[(size_t)st + slot] = 0.0f;
        else if (slot >= 3 && slot - 3 < tail)
            out[(size_t)st + a + 4 * nb + (slot - 3)] = 0.0f;
    }
    // aligned float4 body: flattened over (channel, chunk), 19 iters/thread
    for (int i = tid; i < 32 * 152; i += 256) {
        const int c = i / 152, k = i - c * 152;
        const uint32_t st = base0 + (uint32_t)c * CSTRIDE;
        const int a = (int)((0u - st) & 3u);
        const int nb = (span - a) >> 2;
        if (k < nb)
            *((float4*)(out + (size_t)st + a) + k) = z4;
    }
    __syncthreads();   // drains vmcnt: zeros land before the ones below

    // ---- epilogue part 2: scatter the 1.0s straight from mask registers ----
    if (x < NXS && lane < 32) {
        const size_t rb = (size_t)(((b * 32 + ch) * 961) + y * NYS + x) * TP;
        uint32_t mw[5] = { m0, m1, m2, m3, m4 };
#pragma unroll
        for (int w = 0; w < 5; ++w) {
            uint32_t mm = mw[w];
            while (mm) {                   // <=4 spikes total per (site,ch)
                const int t = __builtin_ctz(mm);
                mm &= mm - 1;
                out[rb + 32 * w + t] = 1.0f;
            }
        }
    }
}

extern "C" void kernel_launch(void* const* d_in, const int* in_sizes, int n_in,
                              void* d_out, int out_size, void* d_ws, size_t ws_size,
                              hipStream_t stream) {
    const float* in = (const float*)d_in[0];   // input_spikes
    const float* wt = (const float*)d_in[1];   // weight
    float* out = (float*)d_out;

    // grid: 16 b x 31 y x 8 x-groups (last group covers 3 sites)
    hipLaunchKernelGGL(snn_wta, dim3(16 * NYS * 8), dim3(256), 0, stream,
                       in, wt, out);
}

// Round 13
// 381.787 us; speedup vs baseline: 1.0106x; 1.0046x over previous
//
#include <hip/hip_runtime.h>
#include <stdint.h>

// Spiking ConvColumn: temporal PWL-response conv + winner-takes-all.
//   input_spikes [16, 2, 64, 64, 100] fp32 (binary)
//   weight       [32, 2, 3, 3]        fp32 in [0,1]
//   output       [16, 32, 31, 31, 149] fp32 (one-hot spikes)
#define NXS 31
#define NYS 31
#define TP 149
#define TT 100
#define RSTRIDE 104         // u32/row: 101 entries + 3 spare; %4==0 keeps b128
                            // alignment; LDS = 54*104*4 = 22.5 KB -> 7 blk/CU
#define NROWS 54            // 2 ci * 3 ky * 9 cols (4 sites share 9 cols)
#define NOUT4 18328192      // 16*32*961*149 / 4 float4s (exact)

// ---------------------------------------------------------------------------
// Kernel A: linear float4 zero-fill of d_out (fillBuffer's access pattern,
// ~5.9 TB/s). The scattered per-block zero-fill was the hidden binder:
// 2384-B spans at 573-KB stride thrash DRAM pages (~3-4 TB/s effective).
// ---------------------------------------------------------------------------
__global__ __launch_bounds__(256) void zero_fill(float4* __restrict__ out)
{
    const float4 z4 = make_float4(0.f, 0.f, 0.f, 0.f);
    const int stride = gridDim.x * 256;
    for (int i = blockIdx.x * 256 + threadIdx.x; i < NOUT4; i += stride)
        out[i] = z4;
}

// ---------------------------------------------------------------------------
// Kernel B: build + jump-scan WTA; writes ONLY the scattered 1.0s (~46 K
// dwords). Zeros are guaranteed by kernel A (stream order).
// Block = 4 waves = sites x0..x0+3 sharing one table set (9 columns).
// Wave lanes: 0-31 = 32 ch x trains 0-8 (ci=0); 32-63 = same ch x 9-17.
// Table entry k = (C[k]<<16)|M[k]: C = #spikes before time k, M = sum times.
// ---------------------------------------------------------------------------
__global__ __launch_bounds__(256) void snn_wta(
    const float* __restrict__ in,
    const float* __restrict__ weight,
    float* __restrict__ out)
{
    __shared__ uint32_t tbl[NROWS * RSTRIDE];

    const int tid  = threadIdx.x;
    const int wave = tid >> 6;
    const int lane = tid & 63;
    const int half = lane >> 5;
    const int ch   = lane & 31;

    const int bi = blockIdx.x;
    const int xg = bi & 7;                // 8 x-groups of 4 (last has 3)
    const int y  = (bi >> 3) % NYS;
    const int b  = bi / (8 * NYS);
    const int x0 = xg * 4;
    const int x  = x0 + wave;             // this wave's site (x>=31 inactive)

    // per-lane response params: r(tau)=tau/16 for tau<=m=floor(16w);
    // (48w-tau)/32 for m<tau<=n=ceil(48w)-1.
    float wA[9]; int mA[9], nA[9];
    {
        const float* wrow = weight + ch * 18 + half * 9;
#pragma unroll
        for (int j = 0; j < 9; ++j) {
            float w = wrow[j];
            float a48 = 48.0f * w;
            int m = (int)floorf(16.0f * w);
            int n = (int)ceilf(a48) - 1;
            if (n < m) n = m;
            wA[j] = a48; mA[j] = m; nA[j] = n;
        }
    }

    // ---- build 54 rows; row r owned by one lane (waves split the rows).
    // Tree-form prefix: 25-step carry chain, b128 entry stores.
    {
        const int r = lane + 14 * wave;    // lanes 0..13 of each wave
        if (lane < 14 && r < NROWS) {
            const int ci = r / 27, rem = r % 27;
            const int ky = rem / 9, col = rem % 9;
            const int h = 2 * y + ky, wc = 2 * x0 + col;
            if (wc < 64) {                 // xg=7,col=8 is OOB and unused
                const float4* rowp = (const float4*)(in +
                    (size_t)(((b * 2 + ci) * 64 + h) * 64 + wc) * TT);
                uint32_t* t = tbl + r * RSTRIDE;      // entry-0, 16B aligned
                uint32_t run = 0;
#pragma unroll 5
                for (int chunk = 0; chunk < 25; ++chunk) {
                    float4 v = rowp[chunk];
                    const uint32_t u = chunk * 4;
                    uint32_t i0 = (v.x > 0.5f) ? ((1u << 16) | u)       : 0u;
                    uint32_t i1 = (v.y > 0.5f) ? ((1u << 16) | (u + 1)) : 0u;
                    uint32_t i2 = (v.z > 0.5f) ? ((1u << 16) | (u + 2)) : 0u;
                    uint32_t i3 = (v.w > 0.5f) ? ((1u << 16) | (u + 3)) : 0u;
                    uint32_t s01 = i0 + i1;
                    uint32_t e1 = run + i0;
                    uint32_t e2 = run + s01;
                    uint32_t e3 = e2 + i2;
                    *((uint4*)(t + u)) = make_uint4(run, e1, e2, e3);
                    run = e3 + i3;         // single dependent add per chunk
                }
                t[100] = run;              // total = entry 100
            }
        }
    }
    __syncthreads();

    // ---- scalar jump-scan WTA ----
    uint32_t m0 = 0, m1 = 0, m2 = 0, m3 = 0, m4 = 0;   // 149-bit spike mask
    if (x < NXS) {
        const uint32_t* Tq = tbl + (half * 27 + 2 * wave) * RSTRIDE;
        int tp = 1;                        // tp=0: empty window, no spike
        while (tp < TP) {
            const int t1 = tp - 1;
            const float ft1 = (float)t1;
            const int b0 = (tp < TT) ? tp : TT;          // uniform per half
            uint32_t P0 = 0, P1 = 0, P2 = 0;
            float F = 0.0f;                // sum_j 48w_j * dc2_j
#pragma unroll
            for (int j = 0; j < 9; ++j) {
                const int roff = ((j / 3) * 9 + (j % 3)) * RSTRIDE; // const
                int i1 = t1 - mA[j]; i1 = i1 < 0 ? 0 : (i1 > TT ? TT : i1);
                int i2 = t1 - nA[j]; i2 = i2 < 0 ? 0 : (i2 > TT ? TT : i2);
                uint32_t p0 = Tq[roff + b0];
                uint32_t p1 = Tq[roff + i1];
                uint32_t p2 = Tq[roff + i2];
                P0 += p0; P1 += p1; P2 += p2;
                F += wA[j] * (float)(int)((p1 - p2) >> 16);
            }
            // packed sums/differences carry-free: sum C<=900, sum M<=44550.
            const uint32_t D1 = P0 - P1;   // rising window totals
            const uint32_t D2 = P1 - P2;   // falling window totals
            float pot = (ft1 * (float)(D1 >> 16) - (float)(D1 & 0xffffu)) * 0.0625f
                      + (F - ft1 * (float)(D2 >> 16) + (float)(D2 & 0xffffu)) * 0.03125f;
            pot += __shfl_xor(pot, 32);    // combine the two train halves

            if (__ballot(pot > 5.4f)) {    // any channel spikes this step?
                // argmax over 32 channels; ties -> lowest ch (jnp.argmax)
                float v = pot; int c = ch;
#pragma unroll
                for (int mk = 16; mk >= 1; mk >>= 1) {
                    float vo = __shfl_xor(v, mk);
                    int co   = __shfl_xor(c, mk);
                    if (vo > v || (vo == v && co < c)) { v = vo; c = co; }
                }
                if (c == ch) {
                    const uint32_t bit = 1u << (tp & 31);
                    switch (tp >> 5) {     // wave-uniform branch
                        case 0: m0 |= bit; break;
                        case 1: m1 |= bit; break;
                        case 2: m2 |= bit; break;
                        case 3: m3 |= bit; break;
                        default: m4 |= bit; break;
                    }
                }
                tp += 48;                  // dep=47 refractory skip
            } else {
                tp += 1;
            }
        }
    }

    // ---- scatter the 1.0s straight from mask registers (zeros came from
    // kernel A, ordered by the stream) ----
    if (x < NXS && lane < 32) {
        const size_t rb = (size_t)(((b * 32 + ch) * 961) + y * NYS + x) * TP;
        uint32_t mw[5] = { m0, m1, m2, m3, m4 };
#pragma unroll
        for (int w = 0; w < 5; ++w) {
            uint32_t mm = mw[w];
            while (mm) {                   // <=4 spikes total per (site,ch)
                const int t = __builtin_ctz(mm);
                mm &= mm - 1;
                out[rb + 32 * w + t] = 1.0f;
            }
        }
    }
}

extern "C" void kernel_launch(void* const* d_in, const int* in_sizes, int n_in,
                              void* d_out, int out_size, void* d_ws, size_t ws_size,
                              hipStream_t stream) {
    const float* in = (const float*)d_in[0];   // input_spikes
    const float* wt = (const float*)d_in[1];   // weight
    float* out = (float*)d_out;

    hipLaunchKernelGGL(zero_fill, dim3(2048), dim3(256), 0, stream,
                       (float4*)out);
    // grid: 16 b x 31 y x 8 x-groups (last group covers 3 sites)
    hipLaunchKernelGGL(snn_wta, dim3(16 * NYS * 8), dim3(256), 0, stream,
                       in, wt, out);
}

// Round 14
// 366.733 us; speedup vs baseline: 1.0520x; 1.0410x over previous
//
#include <hip/hip_runtime.h>
#include <stdint.h>

// Spiking ConvColumn: temporal PWL-response conv + winner-takes-all.
//   input_spikes [16, 2, 64, 64, 100] fp32 (binary)
//   weight       [32, 2, 3, 3]        fp32 in [0,1]
//   output       [16, 32, 31, 31, 149] fp32 (one-hot spikes)
#define NXS 31
#define NYS 31
#define TP 149
#define TT 100
#define RSTRIDE 104         // u32/row: 101 entries + 3 spare; %4==0 keeps b128
                            // alignment; LDS = 54*104*4 = 22.5 KB -> 7 blk/CU
#define NROWS 54            // 2 ci * 3 ky * 9 cols (4 sites share 9 cols)
#define NBLK (16 * NYS * 8) // 3968 blocks
#define FILL4 4619          // float4s per block: 3968*4619 = 18328192 exact
#define NREC (NBLK * 128)   // 492032 (site,ch) mask records in d_ws

// ---------------------------------------------------------------------------
// Kernel 1: build + linear-fill-issue + jump-scan; masks to d_ws.
// The zero-fill is addressed by blockIdx (pure streaming order, fillBuffer
// pattern ~5.9 TB/s) and issued BEFORE the scan, which is LDS/VALU-only ->
// the stores drain underneath the compute. No output ones written here.
// Block = 4 waves = sites x0..x0+3 sharing one table set (9 columns).
// Wave lanes: 0-31 = 32 ch x trains 0-8 (ci=0); 32-63 = same ch x 9-17.
// Table entry k = (C[k]<<16)|M[k]: C = #spikes before time k, M = sum times.
// ---------------------------------------------------------------------------
__global__ __launch_bounds__(256) void snn_scan(
    const float* __restrict__ in,
    const float* __restrict__ weight,
    float* __restrict__ out,
    uint32_t* __restrict__ ws)
{
    __shared__ uint32_t tbl[NROWS * RSTRIDE];

    const int tid  = threadIdx.x;
    const int wave = tid >> 6;
    const int lane = tid & 63;
    const int half = lane >> 5;
    const int ch   = lane & 31;

    const int bi = blockIdx.x;
    const int xg = bi & 7;                // 8 x-groups of 4 (last has 3)
    const int y  = (bi >> 3) % NYS;
    const int b  = bi / (8 * NYS);
    const int x0 = xg * 4;
    const int x  = x0 + wave;             // this wave's site (x>=31 inactive)

    // per-lane response params: r(tau)=tau/16 for tau<=m=floor(16w);
    // (48w-tau)/32 for m<tau<=n=ceil(48w)-1.
    float wA[9]; int mA[9], nA[9];
    {
        const float* wrow = weight + ch * 18 + half * 9;
#pragma unroll
        for (int j = 0; j < 9; ++j) {
            float w = wrow[j];
            float a48 = 48.0f * w;
            int m = (int)floorf(16.0f * w);
            int n = (int)ceilf(a48) - 1;
            if (n < m) n = m;
            wA[j] = a48; mA[j] = m; nA[j] = n;
        }
    }

    // ---- build 54 rows; row r owned by one lane (waves split the rows).
    // Tree-form prefix: 25-step carry chain, b128 entry stores.
    {
        const int r = lane + 14 * wave;    // lanes 0..13 of each wave
        if (lane < 14 && r < NROWS) {
            const int ci = r / 27, rem = r % 27;
            const int ky = rem / 9, col = rem % 9;
            const int h = 2 * y + ky, wc = 2 * x0 + col;
            if (wc < 64) {                 // xg=7,col=8 is OOB and unused
                const float4* rowp = (const float4*)(in +
                    (size_t)(((b * 2 + ci) * 64 + h) * 64 + wc) * TT);
                uint32_t* t = tbl + r * RSTRIDE;      // entry-0, 16B aligned
                uint32_t run = 0;
#pragma unroll 5
                for (int chunk = 0; chunk < 25; ++chunk) {
                    float4 v = rowp[chunk];
                    const uint32_t u = chunk * 4;
                    uint32_t i0 = (v.x > 0.5f) ? ((1u << 16) | u)       : 0u;
                    uint32_t i1 = (v.y > 0.5f) ? ((1u << 16) | (u + 1)) : 0u;
                    uint32_t i2 = (v.z > 0.5f) ? ((1u << 16) | (u + 2)) : 0u;
                    uint32_t i3 = (v.w > 0.5f) ? ((1u << 16) | (u + 3)) : 0u;
                    uint32_t s01 = i0 + i1;
                    uint32_t e1 = run + i0;
                    uint32_t e2 = run + s01;
                    uint32_t e3 = e2 + i2;
                    *((uint4*)(t + u)) = make_uint4(run, e1, e2, e3);
                    run = e3 + i3;         // single dependent add per chunk
                }
                t[100] = run;              // total = entry 100
            }
        }
    }
    __syncthreads();

    // ---- issue linear zero-fill chunk (fire-and-forget; drains under scan).
    // Placed AFTER the barrier so no vmcnt wait lands between here and the
    // kernel end (the scan below is LDS/VALU-only).
    {
        float4* out4 = (float4*)out + (size_t)bi * FILL4;
        const float4 z4 = make_float4(0.f, 0.f, 0.f, 0.f);
        for (int i = tid; i < FILL4; i += 256)
            out4[i] = z4;
    }

    // ---- scalar jump-scan WTA ----
    uint32_t m0 = 0, m1 = 0, m2 = 0, m3 = 0, m4 = 0;   // 149-bit spike mask
    if (x < NXS) {
        const uint32_t* Tq = tbl + (half * 27 + 2 * wave) * RSTRIDE;
        int tp = 1;                        // tp=0: empty window, no spike
        while (tp < TP) {
            const int t1 = tp - 1;
            const float ft1 = (float)t1;
            const int b0 = (tp < TT) ? tp : TT;          // uniform per half
            uint32_t P0 = 0, P1 = 0, P2 = 0;
            float F = 0.0f;                // sum_j 48w_j * dc2_j
#pragma unroll
            for (int j = 0; j < 9; ++j) {
                const int roff = ((j / 3) * 9 + (j % 3)) * RSTRIDE; // const
                int i1 = t1 - mA[j]; i1 = i1 < 0 ? 0 : (i1 > TT ? TT : i1);
                int i2 = t1 - nA[j]; i2 = i2 < 0 ? 0 : (i2 > TT ? TT : i2);
                uint32_t p0 = Tq[roff + b0];
                uint32_t p1 = Tq[roff + i1];
                uint32_t p2 = Tq[roff + i2];
                P0 += p0; P1 += p1; P2 += p2;
                F += wA[j] * (float)(int)((p1 - p2) >> 16);
            }
            // packed sums/differences carry-free: sum C<=900, sum M<=44550.
            const uint32_t D1 = P0 - P1;   // rising window totals
            const uint32_t D2 = P1 - P2;   // falling window totals
            float pot = (ft1 * (float)(D1 >> 16) - (float)(D1 & 0xffffu)) * 0.0625f
                      + (F - ft1 * (float)(D2 >> 16) + (float)(D2 & 0xffffu)) * 0.03125f;
            pot += __shfl_xor(pot, 32);    // combine the two train halves

            if (__ballot(pot > 5.4f)) {    // any channel spikes this step?
                // argmax over 32 channels; ties -> lowest ch (jnp.argmax)
                float v = pot; int c = ch;
#pragma unroll
                for (int mk = 16; mk >= 1; mk >>= 1) {
                    float vo = __shfl_xor(v, mk);
                    int co   = __shfl_xor(c, mk);
                    if (vo > v || (vo == v && co < c)) { v = vo; c = co; }
                }
                if (c == ch) {
                    const uint32_t bit = 1u << (tp & 31);
                    switch (tp >> 5) {     // wave-uniform branch
                        case 0: m0 |= bit; break;
                        case 1: m1 |= bit; break;
                        case 2: m2 |= bit; break;
                        case 3: m3 |= bit; break;
                        default: m4 |= bit; break;
                    }
                }
                tp += 48;                  // dep=47 refractory skip
            } else {
                tp += 1;
            }
        }
    }

    // ---- write this (site,ch) mask record (24 B, records contiguous per
    // block -> 768 B per wave, coalesced). Inactive waves write zeros. ----
    if (lane < 32) {
        uint32_t* rec = ws + ((size_t)bi * 128 + wave * 32 + ch) * 6;
        rec[0] = m0; rec[1] = m1; rec[2] = m2; rec[3] = m3; rec[4] = m4;
    }
}

// ---------------------------------------------------------------------------
// Kernel 2: scatter the 1.0s. One thread per (site,ch) record; coalesced
// 24-B read, early-out if no spikes (~69%), else <=4 scattered stores.
// Kernel boundary guarantees kernel 1's zeros are visible first.
// ---------------------------------------------------------------------------
__global__ __launch_bounds__(256) void snn_scatter(
    const uint32_t* __restrict__ ws,
    float* __restrict__ out)
{
    const int r = blockIdx.x * 256 + threadIdx.x;        // 0..NREC-1
    const uint32_t* rec = ws + (size_t)r * 6;
    const uint32_t m0 = rec[0], m1 = rec[1], m2 = rec[2];
    const uint32_t m3 = rec[3], m4 = rec[4];
    if ((m0 | m1 | m2 | m3 | m4) == 0u) return;

    const int ch = r & 31;
    const int wave = (r >> 5) & 3;
    const int bi = r >> 7;
    const int xg = bi & 7;
    const int y  = (bi >> 3) % NYS;
    const int b  = bi / (8 * NYS);
    const int x  = xg * 4 + wave;                        // x<31 (else mask==0)
    const size_t base = (size_t)(((b * 32 + ch) * 961) + y * NYS + x) * TP;

    uint32_t mw[5] = { m0, m1, m2, m3, m4 };
#pragma unroll
    for (int w = 0; w < 5; ++w) {
        uint32_t mm = mw[w];
        while (mm) {                       // <=4 spikes total per (site,ch)
            const int t = __builtin_ctz(mm);
            mm &= mm - 1;
            out[base + 32 * w + t] = 1.0f;
        }
    }
}

extern "C" void kernel_launch(void* const* d_in, const int* in_sizes, int n_in,
                              void* d_out, int out_size, void* d_ws, size_t ws_size,
                              hipStream_t stream) {
    const float* in = (const float*)d_in[0];   // input_spikes
    const float* wt = (const float*)d_in[1];   // weight
    float* out = (float*)d_out;
    uint32_t* ws = (uint32_t*)d_ws;            // 492032 * 24 B = 11.8 MB

    hipLaunchKernelGGL(snn_scan, dim3(NBLK), dim3(256), 0, stream,
                       in, wt, out, ws);
    hipLaunchKernelGGL(snn_scatter, dim3(NREC / 256), dim3(256), 0, stream,
                       ws, out);
}